// Round 1
// baseline (4765.548 us; speedup 1.0000x reference)
//
#include <hip/hip_runtime.h>
#include <math.h>

#define T_TOK 32768
#define D_DIM 128
#define K_CODE 8192
#define KSPLIT 4
#define KPER (K_CODE / KSPLIT)

// ---------------- proj: C[r][c] = sum_d E[r][d]*W[c][d] + b[c] ----------------
__global__ __launch_bounds__(256) void proj_kernel(const float* __restrict__ E,
                                                   const float* __restrict__ W,
                                                   const float* __restrict__ b,
                                                   float* __restrict__ C) {
    int idx = blockIdx.x * 256 + threadIdx.x;   // r*128 + c
    int r = idx >> 7, c = idx & 127;
    const float4* E4 = (const float4*)(E + (size_t)r * D_DIM);
    const float4* W4 = (const float4*)(W + (size_t)c * D_DIM);
    float4 acc = make_float4(0.f, 0.f, 0.f, 0.f);
#pragma unroll
    for (int dd = 0; dd < 32; ++dd) {
        float4 e = E4[dd], w = W4[dd];
        acc.x = fmaf(e.x, w.x, acc.x);
        acc.y = fmaf(e.y, w.y, acc.y);
        acc.z = fmaf(e.z, w.z, acc.z);
        acc.w = fmaf(e.w, w.w, acc.w);
    }
    C[idx] = ((acc.x + acc.y) + (acc.z + acc.w)) + b[c];
}

// ---------------- cnorm: |c_k|^2 ----------------
__global__ __launch_bounds__(64) void cnorm_kernel(const float* __restrict__ C,
                                                   float* __restrict__ cn) {
    int r = blockIdx.x;
    int l = threadIdx.x;
    float a = C[r * D_DIM + l];
    float b2 = C[r * D_DIM + 64 + l];
    float s = a * a + b2 * b2;
#pragma unroll
    for (int off = 32; off > 0; off >>= 1) s += __shfl_down(s, off, 64);
    if (l == 0) cn[r] = s;
}

// ---------------- argmin over a K-split, one token per lane ----------------
__global__ __launch_bounds__(256, 2) void argmin_kernel(const float* __restrict__ Z,
                                                        const float* __restrict__ C,
                                                        const float* __restrict__ cn,
                                                        float* __restrict__ bv,
                                                        int* __restrict__ bi) {
    int t = blockIdx.x * 256 + threadIdx.x;
    int split = blockIdx.y;

    const float4* Z4 = (const float4*)(Z + (size_t)t * D_DIM);
    float4 zr[32];
#pragma unroll
    for (int dd = 0; dd < 32; ++dd) zr[dd] = Z4[dd];

    float zn = 0.f;
#pragma unroll
    for (int dd = 0; dd < 32; ++dd) {
        float4 z4 = zr[dd];
        zn += z4.x * z4.x;
        zn += z4.y * z4.y;
        zn += z4.z * z4.z;
        zn += z4.w * z4.w;
    }

    const float4* C4 = (const float4*)C;
    float best = 3.4e38f;
    int bidx = split * KPER;

    int k0 = split * KPER;
    for (int k = k0; k < k0 + KPER; k += 4) {
        const float4* cA = C4 + (size_t)k * 32;
        const float4* cB = cA + 32;
        const float4* cC = cA + 64;
        const float4* cD = cA + 96;
        float d0 = 0.f, d1 = 0.f, d2 = 0.f, d3 = 0.f;
#pragma unroll 4
        for (int dd = 0; dd < 32; ++dd) {
            float4 z4 = zr[dd];
            float4 a = cA[dd], b = cB[dd], c = cC[dd], e = cD[dd];
            d0 = fmaf(z4.x, a.x, d0);
            d1 = fmaf(z4.x, b.x, d1);
            d2 = fmaf(z4.x, c.x, d2);
            d3 = fmaf(z4.x, e.x, d3);
            d0 = fmaf(z4.y, a.y, d0);
            d1 = fmaf(z4.y, b.y, d1);
            d2 = fmaf(z4.y, c.y, d2);
            d3 = fmaf(z4.y, e.y, d3);
            d0 = fmaf(z4.z, a.z, d0);
            d1 = fmaf(z4.z, b.z, d1);
            d2 = fmaf(z4.z, c.z, d2);
            d3 = fmaf(z4.z, e.z, d3);
            d0 = fmaf(z4.w, a.w, d0);
            d1 = fmaf(z4.w, b.w, d1);
            d2 = fmaf(z4.w, c.w, d2);
            d3 = fmaf(z4.w, e.w, d3);
        }
        // Match reference rounding: (|z|^2 + |c|^2) - 2*dot, elementwise fp32.
        float s0 = (zn + cn[k + 0]) - 2.f * d0;
        float s1 = (zn + cn[k + 1]) - 2.f * d1;
        float s2 = (zn + cn[k + 2]) - 2.f * d2;
        float s3 = (zn + cn[k + 3]) - 2.f * d3;
        if (s0 < best) { best = s0; bidx = k + 0; }
        if (s1 < best) { best = s1; bidx = k + 1; }
        if (s2 < best) { best = s2; bidx = k + 2; }
        if (s3 < best) { best = s3; bidx = k + 3; }
    }
    bv[(size_t)split * T_TOK + t] = best;
    bi[(size_t)split * T_TOK + t] = bidx;
}

// ---------------- merge splits, histogram counts ----------------
__global__ __launch_bounds__(256) void merge_kernel(const float* __restrict__ bv,
                                                    const int* __restrict__ bi,
                                                    int* __restrict__ idxf,
                                                    int* __restrict__ counts) {
    int t = blockIdx.x * 256 + threadIdx.x;
    float best = bv[t];
    int idx = bi[t];
#pragma unroll
    for (int s = 1; s < KSPLIT; ++s) {
        float v = bv[(size_t)s * T_TOK + t];
        int i2 = bi[(size_t)s * T_TOK + t];
        if (v < best) { best = v; idx = i2; }
    }
    idxf[t] = idx;
    atomicAdd(&counts[idx], 1);
}

// ---------------- gather z_q, write z_q_st, accumulate commit-loss sum ----------------
__global__ __launch_bounds__(256) void zq_kernel(const float* __restrict__ Z,
                                                 const float* __restrict__ C,
                                                 const int* __restrict__ idxf,
                                                 float* __restrict__ out,
                                                 float* __restrict__ loss) {
    int gid = blockIdx.x * 256 + threadIdx.x;   // over T*D/4 = 1048576 float4s
    int t = gid >> 5;                           // 32 float4 per token
    int d4 = gid & 31;
    int idx = idxf[t];
    float4 cv = ((const float4*)C)[(size_t)idx * 32 + d4];
    float4 zv = ((const float4*)Z)[gid];
    float dx = cv.x - zv.x, dy = cv.y - zv.y, dz = cv.z - zv.z, dw = cv.w - zv.w;
    float4 o;
    o.x = zv.x + dx;    // z + (z_q - z): match reference elementwise rounding
    o.y = zv.y + dy;
    o.z = zv.z + dz;
    o.w = zv.w + dw;
    ((float4*)out)[gid] = o;

    float ls = dx * dx + dy * dy + dz * dz + dw * dw;
#pragma unroll
    for (int off = 32; off > 0; off >>= 1) ls += __shfl_down(ls, off, 64);
    __shared__ float red[4];
    int lane = threadIdx.x & 63, w = threadIdx.x >> 6;
    if (lane == 0) red[w] = ls;
    __syncthreads();
    if (threadIdx.x == 0) {
        atomicAdd(loss, (red[0] + red[1]) + (red[2] + red[3]));
    }
}

// ---------------- scalars: commit_loss, perplexity ----------------
__global__ __launch_bounds__(256) void scalars_kernel(const int* __restrict__ counts,
                                                      const float* __restrict__ loss,
                                                      float* __restrict__ out) {
    float s = 0.f;
    for (int i = threadIdx.x; i < K_CODE; i += 256) {
        float e = (float)counts[i] * (1.0f / (float)T_TOK);
        s += e * logf(e + 1e-8f);
    }
#pragma unroll
    for (int off = 32; off > 0; off >>= 1) s += __shfl_down(s, off, 64);
    __shared__ float red[4];
    int lane = threadIdx.x & 63, w = threadIdx.x >> 6;
    if (lane == 0) red[w] = s;
    __syncthreads();
    if (threadIdx.x == 0) {
        float ssum = (red[0] + red[1]) + (red[2] + red[3]);
        out[(size_t)T_TOK * D_DIM + 0] = 1.25f * loss[0] / (float)((size_t)T_TOK * D_DIM);
        out[(size_t)T_TOK * D_DIM + 1] = expf(-ssum);
    }
}

extern "C" void kernel_launch(void* const* d_in, const int* in_sizes, int n_in,
                              void* d_out, int out_size, void* d_ws, size_t ws_size,
                              hipStream_t stream) {
    const float* z   = (const float*)d_in[0];   // [8,4096,128]
    const float* emb = (const float*)d_in[1];   // [8192,128]
    const float* pw  = (const float*)d_in[2];   // [128,128]
    const float* pb  = (const float*)d_in[3];   // [128]
    float* out = (float*)d_out;

    char* ws = (char*)d_ws;
    // layout (bytes):
    //   C:      0        .. 4194304   (8192*128 f32)
    //   cnorm:  4194304  .. 4227072   (8192 f32)
    //   bv:     4227072  .. 4751360   (4*32768 f32)
    //   bi:     4751360  .. 5275648   (4*32768 i32)
    //   idxf:   5275648  .. 5406720   (32768 i32)
    //   counts: 5406720  .. 5439488   (8192 i32)
    //   loss:   5439488  .. 5439492   (1 f32)
    float* C      = (float*)(ws + 0);
    float* cn     = (float*)(ws + 4194304);
    float* bv     = (float*)(ws + 4227072);
    int*   bi     = (int*)  (ws + 4751360);
    int*   idxf   = (int*)  (ws + 5275648);
    int*   counts = (int*)  (ws + 5406720);
    float* loss   = (float*)(ws + 5439488);

    hipMemsetAsync(ws + 5406720, 0, 32768 + 4, stream);   // counts + loss

    proj_kernel<<<(K_CODE * D_DIM) / 256, 256, 0, stream>>>(emb, pw, pb, C);
    cnorm_kernel<<<K_CODE, 64, 0, stream>>>(C, cn);
    argmin_kernel<<<dim3(T_TOK / 256, KSPLIT), 256, 0, stream>>>(z, C, cn, bv, bi);
    merge_kernel<<<T_TOK / 256, 256, 0, stream>>>(bv, bi, idxf, counts);
    zq_kernel<<<(T_TOK * D_DIM / 4) / 256, 256, 0, stream>>>(z, C, idxf, out, loss);
    scalars_kernel<<<1, 256, 0, stream>>>(counts, loss, out);
}

// Round 2
// 2367.483 us; speedup vs baseline: 2.0129x; 2.0129x over previous
//
#include <hip/hip_runtime.h>
#include <math.h>

#define T_TOK 32768
#define D_DIM 128
#define K_CODE 8192
#define KSPLIT 4
#define KPER (K_CODE / KSPLIT)

// ---------------- proj: C[r][c] = sum_d E[r][d]*W[c][d] + b[c] ----------------
__global__ __launch_bounds__(256) void proj_kernel(const float* __restrict__ E,
                                                   const float* __restrict__ W,
                                                   const float* __restrict__ b,
                                                   float* __restrict__ C) {
    int idx = blockIdx.x * 256 + threadIdx.x;   // r*128 + c
    int r = idx >> 7, c = idx & 127;
    const float4* E4 = (const float4*)(E + (size_t)r * D_DIM);
    const float4* W4 = (const float4*)(W + (size_t)c * D_DIM);
    float4 acc = make_float4(0.f, 0.f, 0.f, 0.f);
#pragma unroll
    for (int dd = 0; dd < 32; ++dd) {
        float4 e = E4[dd], w = W4[dd];
        acc.x = fmaf(e.x, w.x, acc.x);
        acc.y = fmaf(e.y, w.y, acc.y);
        acc.z = fmaf(e.z, w.z, acc.z);
        acc.w = fmaf(e.w, w.w, acc.w);
    }
    C[idx] = ((acc.x + acc.y) + (acc.z + acc.w)) + b[c];
}

// ---------------- cnorm: |c_k|^2 ----------------
__global__ __launch_bounds__(64) void cnorm_kernel(const float* __restrict__ C,
                                                   float* __restrict__ cn) {
    int r = blockIdx.x;
    int l = threadIdx.x;
    float a = C[r * D_DIM + l];
    float b2 = C[r * D_DIM + 64 + l];
    float s = a * a + b2 * b2;
#pragma unroll
    for (int off = 32; off > 0; off >>= 1) s += __shfl_down(s, off, 64);
    if (l == 0) cn[r] = s;
}

// ---------------- argmin over a K-split, one token per lane ----------------
// zr must stay in VGPRs: the dd loop is FULLY unrolled so all zr indices are
// compile-time constants (R1 failure: partial unroll -> dynamic index ->
// scratch spill -> 16.8 GB HBM traffic).
__global__ __launch_bounds__(256, 2) void argmin_kernel(const float* __restrict__ Z,
                                                        const float* __restrict__ C,
                                                        const float* __restrict__ cn,
                                                        float* __restrict__ bv,
                                                        int* __restrict__ bi) {
    int t = blockIdx.x * 256 + threadIdx.x;
    int split = blockIdx.y;

    const float4* Z4 = (const float4*)(Z + (size_t)t * D_DIM);
    float4 zr[32];
#pragma unroll
    for (int dd = 0; dd < 32; ++dd) zr[dd] = Z4[dd];

    float zn = 0.f;
#pragma unroll
    for (int dd = 0; dd < 32; ++dd) {
        float4 z4 = zr[dd];
        zn += z4.x * z4.x;
        zn += z4.y * z4.y;
        zn += z4.z * z4.z;
        zn += z4.w * z4.w;
    }

    const float4* C4 = (const float4*)C;
    float best = 3.4e38f;
    int bidx = split * KPER;

    int k0 = split * KPER;
    for (int k = k0; k < k0 + KPER; k += 4) {
        const float4* cA = C4 + (size_t)k * 32;
        const float4* cB = cA + 32;
        const float4* cC = cA + 64;
        const float4* cD = cA + 96;
        float d0 = 0.f, d1 = 0.f, d2 = 0.f, d3 = 0.f;
#pragma unroll
        for (int dd = 0; dd < 32; ++dd) {
            float4 z4 = zr[dd];
            float4 a = cA[dd], b = cB[dd], c = cC[dd], e = cD[dd];
            d0 = fmaf(z4.x, a.x, d0);
            d1 = fmaf(z4.x, b.x, d1);
            d2 = fmaf(z4.x, c.x, d2);
            d3 = fmaf(z4.x, e.x, d3);
            d0 = fmaf(z4.y, a.y, d0);
            d1 = fmaf(z4.y, b.y, d1);
            d2 = fmaf(z4.y, c.y, d2);
            d3 = fmaf(z4.y, e.y, d3);
            d0 = fmaf(z4.z, a.z, d0);
            d1 = fmaf(z4.z, b.z, d1);
            d2 = fmaf(z4.z, c.z, d2);
            d3 = fmaf(z4.z, e.z, d3);
            d0 = fmaf(z4.w, a.w, d0);
            d1 = fmaf(z4.w, b.w, d1);
            d2 = fmaf(z4.w, c.w, d2);
            d3 = fmaf(z4.w, e.w, d3);
        }
        // Match reference rounding: (|z|^2 + |c|^2) - 2*dot, elementwise fp32.
        float s0 = (zn + cn[k + 0]) - 2.f * d0;
        float s1 = (zn + cn[k + 1]) - 2.f * d1;
        float s2 = (zn + cn[k + 2]) - 2.f * d2;
        float s3 = (zn + cn[k + 3]) - 2.f * d3;
        if (s0 < best) { best = s0; bidx = k + 0; }
        if (s1 < best) { best = s1; bidx = k + 1; }
        if (s2 < best) { best = s2; bidx = k + 2; }
        if (s3 < best) { best = s3; bidx = k + 3; }
    }
    bv[(size_t)split * T_TOK + t] = best;
    bi[(size_t)split * T_TOK + t] = bidx;
}

// ---------------- merge splits, histogram counts ----------------
__global__ __launch_bounds__(256) void merge_kernel(const float* __restrict__ bv,
                                                    const int* __restrict__ bi,
                                                    int* __restrict__ idxf,
                                                    int* __restrict__ counts) {
    int t = blockIdx.x * 256 + threadIdx.x;
    float best = bv[t];
    int idx = bi[t];
#pragma unroll
    for (int s = 1; s < KSPLIT; ++s) {
        float v = bv[(size_t)s * T_TOK + t];
        int i2 = bi[(size_t)s * T_TOK + t];
        if (v < best) { best = v; idx = i2; }
    }
    idxf[t] = idx;
    atomicAdd(&counts[idx], 1);
}

// ---------------- gather z_q, write z_q_st, accumulate commit-loss sum ----------------
__global__ __launch_bounds__(256) void zq_kernel(const float* __restrict__ Z,
                                                 const float* __restrict__ C,
                                                 const int* __restrict__ idxf,
                                                 float* __restrict__ out,
                                                 float* __restrict__ loss) {
    int gid = blockIdx.x * 256 + threadIdx.x;   // over T*D/4 = 1048576 float4s
    int t = gid >> 5;                           // 32 float4 per token
    int d4 = gid & 31;
    int idx = idxf[t];
    float4 cv = ((const float4*)C)[(size_t)idx * 32 + d4];
    float4 zv = ((const float4*)Z)[gid];
    float dx = cv.x - zv.x, dy = cv.y - zv.y, dz = cv.z - zv.z, dw = cv.w - zv.w;
    float4 o;
    o.x = zv.x + dx;    // z + (z_q - z): match reference elementwise rounding
    o.y = zv.y + dy;
    o.z = zv.z + dz;
    o.w = zv.w + dw;
    ((float4*)out)[gid] = o;

    float ls = dx * dx + dy * dy + dz * dz + dw * dw;
#pragma unroll
    for (int off = 32; off > 0; off >>= 1) ls += __shfl_down(ls, off, 64);
    __shared__ float red[4];
    int lane = threadIdx.x & 63, w = threadIdx.x >> 6;
    if (lane == 0) red[w] = ls;
    __syncthreads();
    if (threadIdx.x == 0) {
        atomicAdd(loss, (red[0] + red[1]) + (red[2] + red[3]));
    }
}

// ---------------- scalars: commit_loss, perplexity ----------------
__global__ __launch_bounds__(256) void scalars_kernel(const int* __restrict__ counts,
                                                      const float* __restrict__ loss,
                                                      float* __restrict__ out) {
    float s = 0.f;
    for (int i = threadIdx.x; i < K_CODE; i += 256) {
        float e = (float)counts[i] * (1.0f / (float)T_TOK);
        s += e * logf(e + 1e-8f);
    }
#pragma unroll
    for (int off = 32; off > 0; off >>= 1) s += __shfl_down(s, off, 64);
    __shared__ float red[4];
    int lane = threadIdx.x & 63, w = threadIdx.x >> 6;
    if (lane == 0) red[w] = s;
    __syncthreads();
    if (threadIdx.x == 0) {
        float ssum = (red[0] + red[1]) + (red[2] + red[3]);
        out[(size_t)T_TOK * D_DIM + 0] = 1.25f * loss[0] / (float)((size_t)T_TOK * D_DIM);
        out[(size_t)T_TOK * D_DIM + 1] = expf(-ssum);
    }
}

extern "C" void kernel_launch(void* const* d_in, const int* in_sizes, int n_in,
                              void* d_out, int out_size, void* d_ws, size_t ws_size,
                              hipStream_t stream) {
    const float* z   = (const float*)d_in[0];   // [8,4096,128]
    const float* emb = (const float*)d_in[1];   // [8192,128]
    const float* pw  = (const float*)d_in[2];   // [128,128]
    const float* pb  = (const float*)d_in[3];   // [128]
    float* out = (float*)d_out;

    char* ws = (char*)d_ws;
    float* C      = (float*)(ws + 0);
    float* cn     = (float*)(ws + 4194304);
    float* bv     = (float*)(ws + 4227072);
    int*   bi     = (int*)  (ws + 4751360);
    int*   idxf   = (int*)  (ws + 5275648);
    int*   counts = (int*)  (ws + 5406720);
    float* loss   = (float*)(ws + 5439488);

    hipMemsetAsync(ws + 5406720, 0, 32768 + 4, stream);   // counts + loss

    proj_kernel<<<(K_CODE * D_DIM) / 256, 256, 0, stream>>>(emb, pw, pb, C);
    cnorm_kernel<<<K_CODE, 64, 0, stream>>>(C, cn);
    argmin_kernel<<<dim3(T_TOK / 256, KSPLIT), 256, 0, stream>>>(z, C, cn, bv, bi);
    merge_kernel<<<T_TOK / 256, 256, 0, stream>>>(bv, bi, idxf, counts);
    zq_kernel<<<(T_TOK * D_DIM / 4) / 256, 256, 0, stream>>>(z, C, idxf, out, loss);
    scalars_kernel<<<1, 256, 0, stream>>>(counts, loss, out);
}